// Round 1
// baseline (1668.562 us; speedup 1.0000x reference)
//
#include <hip/hip_runtime.h>
#include <cstdint>
#include <cstddef>

#define BN_EPS 1e-5f

// ---------------- utility kernels ----------------

__global__ void k_count(const int* __restrict__ col, int* __restrict__ indeg, int E){
  int e = blockIdx.x*blockDim.x + threadIdx.x;
  if (e < E) atomicAdd(&indeg[col[e]], 1);
}

// exclusive scan, 1024 elems/block
__global__ void k_scan1(const int* __restrict__ in, int* __restrict__ out, int* __restrict__ bsum, int n){
  __shared__ int s[256];
  int t = threadIdx.x;
  int base = blockIdx.x*1024 + t*4;
  int v0 = (base+0 < n) ? in[base+0] : 0;
  int v1 = (base+1 < n) ? in[base+1] : 0;
  int v2 = (base+2 < n) ? in[base+2] : 0;
  int v3 = (base+3 < n) ? in[base+3] : 0;
  int lsum = v0+v1+v2+v3;
  s[t] = lsum;
  __syncthreads();
  for (int off=1; off<256; off<<=1){
    int x = 0;
    if (t >= off) x = s[t-off];
    __syncthreads();
    if (t >= off) s[t] += x;
    __syncthreads();
  }
  int excl = s[t] - lsum;
  if (base+0 < n) out[base+0] = excl;
  if (base+1 < n) out[base+1] = excl + v0;
  if (base+2 < n) out[base+2] = excl + v0 + v1;
  if (base+3 < n) out[base+3] = excl + v0 + v1 + v2;
  if (t == 255) bsum[blockIdx.x] = s[255];
}

__global__ void k_scan2(int* bsum, int nblk){
  if (threadIdx.x==0 && blockIdx.x==0){
    int run = 0;
    for (int i=0;i<nblk;i++){ int t = bsum[i]; bsum[i] = run; run += t; }
  }
}

__global__ void k_scan3(int* __restrict__ out, int* __restrict__ cursor, const int* __restrict__ bsum, int n, int E){
  int i = blockIdx.x*blockDim.x + threadIdx.x;
  if (i < n){
    int v = out[i] + bsum[i>>10];
    out[i] = v;
    cursor[i] = v;
  }
  if (i == 0) out[n] = E;
}

__global__ void k_dinv(const int* __restrict__ indeg, float* __restrict__ dinv, int n){
  int i = blockIdx.x*blockDim.x + threadIdx.x;
  if (i < n) dinv[i] = 1.0f / sqrtf((float)(indeg[i] + 1));
}

__global__ void k_fill(const int* __restrict__ row, const int* __restrict__ col,
                       int* __restrict__ cursor, int* __restrict__ csr, int E){
  int e = blockIdx.x*blockDim.x + threadIdx.x;
  if (e < E){
    int c = col[e];
    int pos = atomicAdd(&cursor[c], 1);
    csr[pos] = row[e];
  }
}

__global__ void k_cnt(const int* __restrict__ batch, int* __restrict__ cnt, int n){
  int i = blockIdx.x*blockDim.x + threadIdx.x;
  if (i < n) atomicAdd(&cnt[batch[i]], 1);
}

// per-column bn finalize: scale = g*rstd, shift = be - mu*scale
__global__ void k_bnfin(const float* __restrict__ region, int F, float invCount,
                        const float* __restrict__ g, const float* __restrict__ be,
                        float* __restrict__ scale, float* __restrict__ shift){
  int i = blockIdx.x*blockDim.x + threadIdx.x;
  if (i >= F) return;
  float s = 0.f, q = 0.f;
  for (int sl = 0; sl < 32; sl++){
    s += region[sl*2*F + i];
    q += region[sl*2*F + F + i];
  }
  float mu  = s * invCount;
  float var = q * invCount - mu*mu;
  if (var < 0.f) var = 0.f;
  float rstd = 1.0f / sqrtf(var + BN_EPS);
  float sc = g[i] * rstd;
  scale[i] = sc;
  shift[i] = be[i] - mu * sc;
}

// emb[g,:] = (cnt>0) ? mean * scale2 + shift2 : 0
__global__ void k_emb(const float* __restrict__ embsum, const int* __restrict__ cnt,
                      const float* __restrict__ sc, const float* __restrict__ sh,
                      float* __restrict__ emb, int G){
  int id = blockIdx.x*blockDim.x + threadIdx.x;
  if (id >= G*64) return;
  int g = id >> 6, l = id & 63;
  float4 s = ((const float4*)embsum)[id];
  int c = cnt[g];
  float4 o = {0.f,0.f,0.f,0.f};
  if (c > 0){
    float inv = 1.0f / (float)c;
    int k = l*4;
    o.x = fmaf(s.x*inv, sc[k+0], sh[k+0]);
    o.y = fmaf(s.y*inv, sc[k+1], sh[k+1]);
    o.z = fmaf(s.z*inv, sc[k+2], sh[k+2]);
    o.w = fmaf(s.w*inv, sc[k+3], sh[k+3]);
  }
  ((float4*)emb)[id] = o;
}

// ---------------- node GEMM: out[i,:] = (affine(A[i,:]) @ W) * dinv[i] ----------------
// BM=64, BN=128 per block, TM=8, TN=4, BK=32
template<int K, int NW, bool AFFINE>
__global__ __launch_bounds__(256) void k_gemm_node(
    const float* __restrict__ A, const float* __restrict__ W,
    const float* __restrict__ scale, const float* __restrict__ shift,
    const float* __restrict__ dinv, float* __restrict__ out, int nrows)
{
  __shared__ float As[32*68];
  __shared__ float Bs[32*128];
  int m0 = blockIdx.x*64;
  int n0 = blockIdx.y*128;
  int tid  = threadIdx.x;
  int tcol = tid & 31, trow = tid >> 5;
  float acc[8][4] = {};
  for (int kc0 = 0; kc0 < K; kc0 += 32){
    #pragma unroll
    for (int j = 0; j < 2; j++){
      int fid = tid + j*256;
      int rr = fid >> 3; int k4 = (fid & 7) << 2;
      int row = m0 + rr;
      float4 v = {0.f,0.f,0.f,0.f};
      if (row < nrows) v = *(const float4*)(A + (size_t)row*K + kc0 + k4);
      if constexpr (AFFINE){
        float4 scv = *(const float4*)(scale + kc0 + k4);
        float4 shv = *(const float4*)(shift + kc0 + k4);
        v.x = fmaf(v.x, scv.x, shv.x);
        v.y = fmaf(v.y, scv.y, shv.y);
        v.z = fmaf(v.z, scv.z, shv.z);
        v.w = fmaf(v.w, scv.w, shv.w);
      }
      As[(k4+0)*68 + rr] = v.x;
      As[(k4+1)*68 + rr] = v.y;
      As[(k4+2)*68 + rr] = v.z;
      As[(k4+3)*68 + rr] = v.w;
    }
    #pragma unroll
    for (int j = 0; j < 4; j++){
      int fid = tid + j*256;
      int kk = fid >> 5; int c4 = (fid & 31) << 2;
      float4 v = *(const float4*)(W + (size_t)(kc0+kk)*NW + n0 + c4);
      *(float4*)(Bs + kk*128 + c4) = v;
    }
    __syncthreads();
    #pragma unroll
    for (int kk = 0; kk < 32; kk++){
      float4 b  = *(const float4*)(Bs + kk*128 + tcol*4);
      float4 a0 = *(const float4*)(As + kk*68 + trow*8);
      float4 a1 = *(const float4*)(As + kk*68 + trow*8 + 4);
      float a[8] = {a0.x,a0.y,a0.z,a0.w,a1.x,a1.y,a1.z,a1.w};
      #pragma unroll
      for (int r = 0; r < 8; r++){
        acc[r][0] = fmaf(a[r], b.x, acc[r][0]);
        acc[r][1] = fmaf(a[r], b.y, acc[r][1]);
        acc[r][2] = fmaf(a[r], b.z, acc[r][2]);
        acc[r][3] = fmaf(a[r], b.w, acc[r][3]);
      }
    }
    __syncthreads();
  }
  #pragma unroll
  for (int r = 0; r < 8; r++){
    int row = m0 + trow*8 + r;
    if (row < nrows){
      float d = dinv[row];
      float4 o = {acc[r][0]*d, acc[r][1]*d, acc[r][2]*d, acc[r][3]*d};
      *(float4*)(out + (size_t)row*NW + n0 + tcol*4) = o;
    }
  }
}

// ---------------- MLP GEMM: out = relu(A @ W + bias), + bn stats ----------------
template<int K, int NWTOT, bool CONCAT, bool AFFINE>
__global__ __launch_bounds__(256) void k_gemm_mlp(
    const float* __restrict__ A0, const float* __restrict__ A1,
    const float* __restrict__ W,
    const float* __restrict__ scale, const float* __restrict__ shift,
    const float* __restrict__ bias,
    float* __restrict__ out, float* __restrict__ gstats, int nrows)
{
  __shared__ float As[32*68];
  __shared__ float Bs[32*128];
  __shared__ float s_sum[128], s_sq[128];
  int m0 = blockIdx.x*64;
  int n0 = blockIdx.y*128;
  int tid  = threadIdx.x;
  int tcol = tid & 31, trow = tid >> 5;
  float acc[8][4] = {};
  constexpr int NCH = (K + 31) / 32;
  for (int ch = 0; ch < NCH; ch++){
    int kc0 = ch*32;
    #pragma unroll
    for (int j = 0; j < 2; j++){
      int fid = tid + j*256;
      int rr = fid >> 3; int k4 = (fid & 7) << 2;
      int row = m0 + rr;
      int kg = kc0 + k4;
      float4 v = {0.f,0.f,0.f,0.f};
      if (row < nrows){
        if constexpr (CONCAT){
          if (kg < 256)      v = *(const float4*)(A0 + (size_t)row*256 + kg);
          else if (kg < 456) v = *(const float4*)(A1 + (size_t)row*200 + (kg-256));
        } else {
          v = *(const float4*)(A0 + (size_t)row*K + kg);
        }
      }
      if constexpr (AFFINE){
        float4 scv = *(const float4*)(scale + kg);
        float4 shv = *(const float4*)(shift + kg);
        v.x = fmaf(v.x, scv.x, shv.x);
        v.y = fmaf(v.y, scv.y, shv.y);
        v.z = fmaf(v.z, scv.z, shv.z);
        v.w = fmaf(v.w, scv.w, shv.w);
      }
      As[(k4+0)*68 + rr] = v.x;
      As[(k4+1)*68 + rr] = v.y;
      As[(k4+2)*68 + rr] = v.z;
      As[(k4+3)*68 + rr] = v.w;
    }
    #pragma unroll
    for (int j = 0; j < 4; j++){
      int fid = tid + j*256;
      int kk = fid >> 5; int c4 = (fid & 31) << 2;
      int kg = kc0 + kk;
      float4 v = {0.f,0.f,0.f,0.f};
      if (kg < K) v = *(const float4*)(W + (size_t)kg*NWTOT + n0 + c4);
      *(float4*)(Bs + kk*128 + c4) = v;
    }
    __syncthreads();
    #pragma unroll
    for (int kk = 0; kk < 32; kk++){
      float4 b  = *(const float4*)(Bs + kk*128 + tcol*4);
      float4 a0 = *(const float4*)(As + kk*68 + trow*8);
      float4 a1 = *(const float4*)(As + kk*68 + trow*8 + 4);
      float a[8] = {a0.x,a0.y,a0.z,a0.w,a1.x,a1.y,a1.z,a1.w};
      #pragma unroll
      for (int r = 0; r < 8; r++){
        acc[r][0] = fmaf(a[r], b.x, acc[r][0]);
        acc[r][1] = fmaf(a[r], b.y, acc[r][1]);
        acc[r][2] = fmaf(a[r], b.z, acc[r][2]);
        acc[r][3] = fmaf(a[r], b.w, acc[r][3]);
      }
    }
    __syncthreads();
  }
  for (int i = tid; i < 128; i += 256){ s_sum[i] = 0.f; s_sq[i] = 0.f; }
  __syncthreads();
  float4 bv = *(const float4*)(bias + n0 + tcol*4);
  float psum[4] = {0,0,0,0}, psq[4] = {0,0,0,0};
  #pragma unroll
  for (int r = 0; r < 8; r++){
    int row = m0 + trow*8 + r;
    if (row < nrows){
      float4 o;
      o.x = fmaxf(acc[r][0] + bv.x, 0.f);
      o.y = fmaxf(acc[r][1] + bv.y, 0.f);
      o.z = fmaxf(acc[r][2] + bv.z, 0.f);
      o.w = fmaxf(acc[r][3] + bv.w, 0.f);
      *(float4*)(out + (size_t)row*NWTOT + n0 + tcol*4) = o;
      psum[0] += o.x; psq[0] += o.x*o.x;
      psum[1] += o.y; psq[1] += o.y*o.y;
      psum[2] += o.z; psq[2] += o.z*o.z;
      psum[3] += o.w; psq[3] += o.w*o.w;
    }
  }
  int f0 = tcol*4;
  atomicAdd(&s_sum[f0+0], psum[0]); atomicAdd(&s_sq[f0+0], psq[0]);
  atomicAdd(&s_sum[f0+1], psum[1]); atomicAdd(&s_sq[f0+1], psq[1]);
  atomicAdd(&s_sum[f0+2], psum[2]); atomicAdd(&s_sq[f0+2], psq[2]);
  atomicAdd(&s_sum[f0+3], psum[3]); atomicAdd(&s_sq[f0+3], psq[3]);
  __syncthreads();
  float* gs = gstats + (size_t)(blockIdx.x & 31)*(2*NWTOT);
  for (int i = tid; i < 128; i += 256){
    atomicAdd(&gs[n0 + i], s_sum[i]);
    atomicAdd(&gs[NWTOT + n0 + i], s_sq[i]);
  }
}

// ---------------- gather layer 1: F=128, 32 threads/node ----------------
__global__ __launch_bounds__(256) void k_gather1(
    const float4* __restrict__ y, const int* __restrict__ offs, const int* __restrict__ csr,
    const float* __restrict__ dinv, const float* __restrict__ bias,
    float4* __restrict__ hout, float* __restrict__ gstats, int N)
{
  __shared__ float s_sum[128], s_sq[128];
  for (int i = threadIdx.x; i < 128; i += 256){ s_sum[i] = 0.f; s_sq[i] = 0.f; }
  __syncthreads();
  int lane = threadIdx.x & 31;
  int sub  = threadIdx.x >> 5;
  int node = blockIdx.x*8 + sub;
  if (node < N){
    int s = offs[node], e = offs[node+1];
    float ax=0.f, ay=0.f, az=0.f, aw=0.f;
    int i = s;
    for (; i + 2 <= e; i += 2){
      int r0 = csr[i], r1 = csr[i+1];
      float4 v0 = y[r0*32 + lane];
      float4 v1 = y[r1*32 + lane];
      ax += v0.x + v1.x; ay += v0.y + v1.y;
      az += v0.z + v1.z; aw += v0.w + v1.w;
    }
    if (i < e){
      int r0 = csr[i];
      float4 v0 = y[r0*32 + lane];
      ax += v0.x; ay += v0.y; az += v0.z; aw += v0.w;
    }
    float4 sf = y[node*32 + lane];
    float dc = dinv[node];
    float4 b4 = ((const float4*)bias)[lane];
    float4 h;
    h.x = fmaxf(fmaf(dc, ax + sf.x, b4.x), 0.f);
    h.y = fmaxf(fmaf(dc, ay + sf.y, b4.y), 0.f);
    h.z = fmaxf(fmaf(dc, az + sf.z, b4.z), 0.f);
    h.w = fmaxf(fmaf(dc, aw + sf.w, b4.w), 0.f);
    hout[node*32 + lane] = h;
    int f0 = lane*4;
    atomicAdd(&s_sum[f0+0], h.x); atomicAdd(&s_sq[f0+0], h.x*h.x);
    atomicAdd(&s_sum[f0+1], h.y); atomicAdd(&s_sq[f0+1], h.y*h.y);
    atomicAdd(&s_sum[f0+2], h.z); atomicAdd(&s_sq[f0+2], h.z*h.z);
    atomicAdd(&s_sum[f0+3], h.w); atomicAdd(&s_sq[f0+3], h.w*h.w);
  }
  __syncthreads();
  float* gs = gstats + (size_t)(blockIdx.x & 31)*(2*128);
  for (int i = threadIdx.x; i < 128; i += 256){
    atomicAdd(&gs[i], s_sum[i]);
    atomicAdd(&gs[128 + i], s_sq[i]);
  }
}

// ---------------- gather layer 2 + pool: F=256, 64 threads/node ----------------
__global__ __launch_bounds__(256) void k_gather2(
    const float4* __restrict__ y, const int* __restrict__ offs, const int* __restrict__ csr,
    const float* __restrict__ dinv, const float* __restrict__ bias, const int* __restrict__ batch,
    float* __restrict__ embsum, float* __restrict__ gstats, int N)
{
  __shared__ float s_sum[256], s_sq[256];
  for (int i = threadIdx.x; i < 256; i += 256){ s_sum[i] = 0.f; s_sq[i] = 0.f; }
  __syncthreads();
  int lane = threadIdx.x & 63;
  int sub  = threadIdx.x >> 6;
  int node = blockIdx.x*4 + sub;
  if (node < N){
    int s = offs[node], e = offs[node+1];
    float ax=0.f, ay=0.f, az=0.f, aw=0.f;
    int i = s;
    for (; i + 2 <= e; i += 2){
      int r0 = csr[i], r1 = csr[i+1];
      float4 v0 = y[r0*64 + lane];
      float4 v1 = y[r1*64 + lane];
      ax += v0.x + v1.x; ay += v0.y + v1.y;
      az += v0.z + v1.z; aw += v0.w + v1.w;
    }
    if (i < e){
      int r0 = csr[i];
      float4 v0 = y[r0*64 + lane];
      ax += v0.x; ay += v0.y; az += v0.z; aw += v0.w;
    }
    float4 sf = y[node*64 + lane];
    float dc = dinv[node];
    float4 b4 = ((const float4*)bias)[lane];
    float4 h;
    h.x = fmaxf(fmaf(dc, ax + sf.x, b4.x), 0.f);
    h.y = fmaxf(fmaf(dc, ay + sf.y, b4.y), 0.f);
    h.z = fmaxf(fmaf(dc, az + sf.z, b4.z), 0.f);
    h.w = fmaxf(fmaf(dc, aw + sf.w, b4.w), 0.f);
    int b = batch[node];
    float* es = embsum + (size_t)b*256 + lane*4;
    atomicAdd(&es[0], h.x); atomicAdd(&es[1], h.y);
    atomicAdd(&es[2], h.z); atomicAdd(&es[3], h.w);
    int f0 = lane*4;
    atomicAdd(&s_sum[f0+0], h.x); atomicAdd(&s_sq[f0+0], h.x*h.x);
    atomicAdd(&s_sum[f0+1], h.y); atomicAdd(&s_sq[f0+1], h.y*h.y);
    atomicAdd(&s_sum[f0+2], h.z); atomicAdd(&s_sq[f0+2], h.z*h.z);
    atomicAdd(&s_sum[f0+3], h.w); atomicAdd(&s_sq[f0+3], h.w*h.w);
  }
  __syncthreads();
  float* gs = gstats + (size_t)(blockIdx.x & 31)*(2*256);
  for (int i = threadIdx.x; i < 256; i += 256){
    atomicAdd(&gs[i], s_sum[i]);
    atomicAdd(&gs[256 + i], s_sq[i]);
  }
}

// ---------------- final: out[g] = bn4(a2[g,:]) . mW3 + mb3 ----------------
__global__ __launch_bounds__(256) void k_final(
    const float* __restrict__ a2, const float* __restrict__ sc, const float* __restrict__ sh,
    const float* __restrict__ w, const float* __restrict__ b, float* __restrict__ out, int G)
{
  int gid  = blockIdx.x*blockDim.x + threadIdx.x;
  int wid  = gid >> 6;
  int lane = gid & 63;
  if (wid >= G) return;
  float2 v = ((const float2*)(a2 + (size_t)wid*128))[lane];
  int k = lane*2;
  float s = fmaf(v.x, sc[k], sh[k]) * w[k] + fmaf(v.y, sc[k+1], sh[k+1]) * w[k+1];
  #pragma unroll
  for (int o = 32; o > 0; o >>= 1) s += __shfl_down(s, o, 64);
  if (lane == 0) out[wid] = s + b[0];
}

// ---------------- launcher ----------------
extern "C" void kernel_launch(void* const* d_in, const int* in_sizes, int n_in,
                              void* d_out, int out_size, void* d_ws, size_t ws_size,
                              hipStream_t stream)
{
  (void)n_in; (void)out_size; (void)ws_size;
  const float* x    = (const float*)d_in[0];
  const int*   ei   = (const int*)d_in[1];
  const int*   batch= (const int*)d_in[2];
  const float* rdk  = (const float*)d_in[3];
  const float* W1   = (const float*)d_in[4];
  const float* b1   = (const float*)d_in[5];
  const float* g1   = (const float*)d_in[6];
  const float* be1  = (const float*)d_in[7];
  const float* W2   = (const float*)d_in[8];
  const float* b2   = (const float*)d_in[9];
  const float* g2   = (const float*)d_in[10];
  const float* be2  = (const float*)d_in[11];
  const float* mW1  = (const float*)d_in[12];
  const float* mb1  = (const float*)d_in[13];
  const float* mg1  = (const float*)d_in[14];
  const float* mbe1 = (const float*)d_in[15];
  const float* mW2  = (const float*)d_in[16];
  const float* mb2  = (const float*)d_in[17];
  const float* mg2  = (const float*)d_in[18];
  const float* mbe2 = (const float*)d_in[19];
  const float* mW3  = (const float*)d_in[20];
  const float* mb3  = (const float*)d_in[21];

  const int N = in_sizes[0] / 64;
  const int E = in_sizes[1] / 2;
  const int G = in_sizes[3] / 200;
  const int* erow = ei;
  const int* ecol = ei + E;

  size_t off = 0;
  auto alloc = [&](size_t bytes)->char*{
    char* p = (char*)d_ws + off;
    off += (bytes + 255) & ~(size_t)255;
    return p;
  };
  int*   indeg  = (int*)  alloc((size_t)N*4);
  int*   offs   = (int*)  alloc(((size_t)N+1)*4);
  int*   cursor = (int*)  alloc((size_t)N*4);
  int*   csr    = (int*)  alloc((size_t)E*4);
  float* dinv   = (float*)alloc((size_t)N*4);
  int*   bsum   = (int*)  alloc(1024*4);
  float* y1     = (float*)alloc((size_t)N*128*4);
  float* h1     = (float*)alloc((size_t)N*128*4);
  float* y2     = (float*)alloc((size_t)N*256*4);
  float* embsum = (float*)alloc((size_t)G*256*4);
  int*   cnt    = (int*)  alloc((size_t)G*4);
  float* emb    = (float*)alloc((size_t)G*256*4);
  float* a1     = (float*)alloc((size_t)G*256*4);
  float* a2     = (float*)alloc((size_t)G*128*4);
  float* gstats = (float*)alloc((size_t)4*32*2*256*4);
  float* scsh   = (float*)alloc((size_t)4*2*256*4);

  float* gs0 = gstats;
  float* gs1 = gstats + 32*2*256;
  float* gs2 = gstats + 2*32*2*256;
  float* gs3 = gstats + 3*32*2*256;
  float* sc1 = scsh;        float* sh1 = scsh + 256;
  float* sc2 = scsh + 512;  float* sh2 = scsh + 768;
  float* sc3 = scsh + 1024; float* sh3 = scsh + 1280;
  float* sc4 = scsh + 1536; float* sh4 = scsh + 1792;

  hipMemsetAsync(indeg,  0, (size_t)N*4, stream);
  hipMemsetAsync(gstats, 0, (size_t)4*32*2*256*4, stream);
  hipMemsetAsync(embsum, 0, (size_t)G*256*4, stream);
  hipMemsetAsync(cnt,    0, (size_t)G*4, stream);

  int nblkE = (E + 255) / 256;
  int nblkN = (N + 255) / 256;
  int nscan = (N + 1023) / 1024;
  int mblk  = (N + 63) / 64;
  int gblk  = (G + 63) / 64;

  k_count<<<nblkE,256,0,stream>>>(ecol, indeg, E);
  k_scan1<<<nscan,256,0,stream>>>(indeg, offs, bsum, N);
  k_scan2<<<1,64,0,stream>>>(bsum, nscan);
  k_scan3<<<nblkN,256,0,stream>>>(offs, cursor, bsum, N, E);
  k_dinv<<<nblkN,256,0,stream>>>(indeg, dinv, N);
  k_fill<<<nblkE,256,0,stream>>>(erow, ecol, cursor, csr, E);

  k_gemm_node<64,128,false><<<dim3(mblk,1),256,0,stream>>>(x, W1, nullptr, nullptr, dinv, y1, N);
  k_gather1<<<(N+7)/8,256,0,stream>>>((const float4*)y1, offs, csr, dinv, b1, (float4*)h1, gs0, N);
  k_bnfin<<<1,256,0,stream>>>(gs0, 128, 1.0f/(float)N, g1, be1, sc1, sh1);

  k_gemm_node<128,256,true><<<dim3(mblk,2),256,0,stream>>>(h1, W2, sc1, sh1, dinv, y2, N);
  k_cnt<<<nblkN,256,0,stream>>>(batch, cnt, N);
  k_gather2<<<(N+3)/4,256,0,stream>>>((const float4*)y2, offs, csr, dinv, b2, batch, embsum, gs1, N);
  k_bnfin<<<1,256,0,stream>>>(gs1, 256, 1.0f/(float)N, g2, be2, sc2, sh2);

  k_emb<<<(G*64+255)/256,256,0,stream>>>(embsum, cnt, sc2, sh2, emb, G);
  k_gemm_mlp<456,256,true,false><<<dim3(gblk,2),256,0,stream>>>(emb, rdk, mW1, nullptr, nullptr, mb1, a1, gs2, G);
  k_bnfin<<<1,256,0,stream>>>(gs2, 256, 1.0f/(float)G, mg1, mbe1, sc3, sh3);
  k_gemm_mlp<256,128,false,true><<<dim3(gblk,1),256,0,stream>>>(a1, nullptr, mW2, sc3, sh3, mb2, a2, gs3, G);
  k_bnfin<<<1,256,0,stream>>>(gs3, 128, 1.0f/(float)G, mg2, mbe2, sc4, sh4);
  k_final<<<(G+3)/4,256,0,stream>>>(a2, sc4, sh4, mW3, mb3, (float*)d_out, G);
}

// Round 2
// 1024.978 us; speedup vs baseline: 1.6279x; 1.6279x over previous
//
#include <hip/hip_runtime.h>
#include <cstdint>
#include <cstddef>

#define BN_EPS 1e-5f

// ---------------- utility kernels ----------------

__device__ inline uint16_t f2bf(float f){
  union {float f; uint32_t u;} v; v.f = f;
  uint32_t u = v.u;
  return (uint16_t)((u + 0x7FFFu + ((u >> 16) & 1u)) >> 16);
}

__device__ inline void bf2f2(uint32_t w, float& a, float& b){
  union {uint32_t u; float f;} ua, ub;
  ua.u = w << 16; ub.u = w & 0xFFFF0000u;
  a = ua.f; b = ub.f;
}

__global__ void k_count(const int* __restrict__ col, int* __restrict__ indeg, int E){
  int e = blockIdx.x*blockDim.x + threadIdx.x;
  if (e < E) atomicAdd(&indeg[col[e]], 1);
}

// exclusive scan, 1024 elems/block
__global__ void k_scan1(const int* __restrict__ in, int* __restrict__ out, int* __restrict__ bsum, int n){
  __shared__ int s[256];
  int t = threadIdx.x;
  int base = blockIdx.x*1024 + t*4;
  int v0 = (base+0 < n) ? in[base+0] : 0;
  int v1 = (base+1 < n) ? in[base+1] : 0;
  int v2 = (base+2 < n) ? in[base+2] : 0;
  int v3 = (base+3 < n) ? in[base+3] : 0;
  int lsum = v0+v1+v2+v3;
  s[t] = lsum;
  __syncthreads();
  for (int off=1; off<256; off<<=1){
    int x = 0;
    if (t >= off) x = s[t-off];
    __syncthreads();
    if (t >= off) s[t] += x;
    __syncthreads();
  }
  int excl = s[t] - lsum;
  if (base+0 < n) out[base+0] = excl;
  if (base+1 < n) out[base+1] = excl + v0;
  if (base+2 < n) out[base+2] = excl + v0 + v1;
  if (base+3 < n) out[base+3] = excl + v0 + v1 + v2;
  if (t == 255) bsum[blockIdx.x] = s[255];
}

// exclusive scan of block sums (nblk <= 128)
__global__ void k_scan2(int* bsum, int nblk){
  __shared__ int s[128];
  int t = threadIdx.x;
  int v = (t < nblk) ? bsum[t] : 0;
  s[t] = v;
  __syncthreads();
  for (int off=1; off<128; off<<=1){
    int x = 0;
    if (t >= off) x = s[t-off];
    __syncthreads();
    if (t >= off) s[t] += x;
    __syncthreads();
  }
  if (t < nblk) bsum[t] = s[t] - v;
}

__global__ void k_scan3(int* __restrict__ out, int* __restrict__ cursor, const int* __restrict__ bsum, int n, int E){
  int i = blockIdx.x*blockDim.x + threadIdx.x;
  if (i < n){
    int v = out[i] + bsum[i>>10];
    out[i] = v;
    cursor[i] = v;
  }
  if (i == 0) out[n] = E;
}

__global__ void k_dinv(const int* __restrict__ indeg, float* __restrict__ dinv, int n){
  int i = blockIdx.x*blockDim.x + threadIdx.x;
  if (i < n) dinv[i] = 1.0f / sqrtf((float)(indeg[i] + 1));
}

__global__ void k_fill(const int* __restrict__ row, const int* __restrict__ col,
                       int* __restrict__ cursor, int* __restrict__ csr, int E){
  int e = blockIdx.x*blockDim.x + threadIdx.x;
  if (e < E){
    int c = col[e];
    int pos = atomicAdd(&cursor[c], 1);
    csr[pos] = row[e];
  }
}

__global__ void k_cnt(const int* __restrict__ batch, int* __restrict__ cnt, int n){
  int i = blockIdx.x*blockDim.x + threadIdx.x;
  if (i < n) atomicAdd(&cnt[batch[i]], 1);
}

// per-column bn finalize: scale = g*rstd, shift = be - mu*scale
__global__ void k_bnfin(const float* __restrict__ region, int F, float invCount,
                        const float* __restrict__ g, const float* __restrict__ be,
                        float* __restrict__ scale, float* __restrict__ shift){
  int i = blockIdx.x*blockDim.x + threadIdx.x;
  if (i >= F) return;
  float s = 0.f, q = 0.f;
  for (int sl = 0; sl < 32; sl++){
    s += region[sl*2*F + i];
    q += region[sl*2*F + F + i];
  }
  float mu  = s * invCount;
  float var = q * invCount - mu*mu;
  if (var < 0.f) var = 0.f;
  float rstd = 1.0f / sqrtf(var + BN_EPS);
  float sc = g[i] * rstd;
  scale[i] = sc;
  shift[i] = be[i] - mu * sc;
}

// xs = bf16(x * dinv[node]) : N x 64
__global__ void k_prep1(const float4* __restrict__ x, const float* __restrict__ dinv,
                        ushort4* __restrict__ xs, int N){
  int id = blockIdx.x*blockDim.x + threadIdx.x;
  if (id >= N*16) return;
  int row = id >> 4;
  float d = dinv[row];
  float4 v = x[id];
  ushort4 o;
  o.x = f2bf(v.x*d); o.y = f2bf(v.y*d); o.z = f2bf(v.z*d); o.w = f2bf(v.w*d);
  xs[id] = o;
}

// hs = bf16((h1*sc1 + sh1) * dinv[node]) : N x 128
__global__ void k_prep2(const float4* __restrict__ h1, const float* __restrict__ dinv,
                        const float4* __restrict__ sc, const float4* __restrict__ sh,
                        ushort4* __restrict__ hs, int N){
  int id = blockIdx.x*blockDim.x + threadIdx.x;
  if (id >= N*32) return;
  int row = id >> 5, lane = id & 31;
  float d = dinv[row];
  float4 v = h1[id];
  float4 s4 = sc[lane], h4 = sh[lane];
  ushort4 o;
  o.x = f2bf(fmaf(v.x, s4.x, h4.x)*d);
  o.y = f2bf(fmaf(v.y, s4.y, h4.y)*d);
  o.z = f2bf(fmaf(v.z, s4.z, h4.z)*d);
  o.w = f2bf(fmaf(v.w, s4.w, h4.w)*d);
  hs[id] = o;
}

// emb[g,:] = (cnt>0) ? mean * scale2 + shift2 : 0
__global__ void k_emb(const float* __restrict__ embsum, const int* __restrict__ cnt,
                      const float* __restrict__ sc, const float* __restrict__ sh,
                      float* __restrict__ emb, int G){
  int id = blockIdx.x*blockDim.x + threadIdx.x;
  if (id >= G*64) return;
  int g = id >> 6, l = id & 63;
  float4 s = ((const float4*)embsum)[id];
  int c = cnt[g];
  float4 o = {0.f,0.f,0.f,0.f};
  if (c > 0){
    float inv = 1.0f / (float)c;
    int k = l*4;
    o.x = fmaf(s.x*inv, sc[k+0], sh[k+0]);
    o.y = fmaf(s.y*inv, sc[k+1], sh[k+1]);
    o.z = fmaf(s.z*inv, sc[k+2], sh[k+2]);
    o.w = fmaf(s.w*inv, sc[k+3], sh[k+3]);
  }
  ((float4*)emb)[id] = o;
}

// ---------------- aggregation (gather) kernels, bf16 payload ----------------
// agg1: z1[c,:] = dinv[c] * (sum_{r in N(c)} xs[r,:] + xs[c,:]), F=64, 8 lanes/node
__global__ __launch_bounds__(256) void k_agg1(
    const uint4* __restrict__ xs, const int* __restrict__ offs, const int* __restrict__ csr,
    const float* __restrict__ dinv, float* __restrict__ z, int N)
{
  int sub = threadIdx.x >> 3, lane = threadIdx.x & 7;
  int node = blockIdx.x*32 + sub;
  if (node >= N) return;
  int s = offs[node], e = offs[node+1];
  float acc[8] = {};
  auto add8 = [&](uint4 v){
    float f0,f1,f2,f3,f4,f5,f6,f7;
    bf2f2(v.x, f0, f1); bf2f2(v.y, f2, f3);
    bf2f2(v.z, f4, f5); bf2f2(v.w, f6, f7);
    acc[0]+=f0; acc[1]+=f1; acc[2]+=f2; acc[3]+=f3;
    acc[4]+=f4; acc[5]+=f5; acc[6]+=f6; acc[7]+=f7;
  };
  int i = s;
  for (; i + 2 <= e; i += 2){
    int r0 = csr[i], r1 = csr[i+1];
    uint4 v0 = xs[r0*8 + lane];
    uint4 v1 = xs[r1*8 + lane];
    add8(v0); add8(v1);
  }
  if (i < e){
    uint4 v0 = xs[csr[i]*8 + lane];
    add8(v0);
  }
  add8(xs[node*8 + lane]);
  float d = dinv[node];
  float4 o0 = {acc[0]*d, acc[1]*d, acc[2]*d, acc[3]*d};
  float4 o1 = {acc[4]*d, acc[5]*d, acc[6]*d, acc[7]*d};
  ((float4*)z)[node*16 + lane*2 + 0] = o0;
  ((float4*)z)[node*16 + lane*2 + 1] = o1;
}

// agg2: z2[c,:] = dinv[c] * (sum hs[r,:] + hs[c,:]), F=128, 16 lanes/node
__global__ __launch_bounds__(256) void k_agg2(
    const uint4* __restrict__ hs, const int* __restrict__ offs, const int* __restrict__ csr,
    const float* __restrict__ dinv, float* __restrict__ z, int N)
{
  int sub = threadIdx.x >> 4, lane = threadIdx.x & 15;
  int node = blockIdx.x*16 + sub;
  if (node >= N) return;
  int s = offs[node], e = offs[node+1];
  float acc[8] = {};
  auto add8 = [&](uint4 v){
    float f0,f1,f2,f3,f4,f5,f6,f7;
    bf2f2(v.x, f0, f1); bf2f2(v.y, f2, f3);
    bf2f2(v.z, f4, f5); bf2f2(v.w, f6, f7);
    acc[0]+=f0; acc[1]+=f1; acc[2]+=f2; acc[3]+=f3;
    acc[4]+=f4; acc[5]+=f5; acc[6]+=f6; acc[7]+=f7;
  };
  int i = s;
  for (; i + 2 <= e; i += 2){
    int r0 = csr[i], r1 = csr[i+1];
    uint4 v0 = hs[r0*16 + lane];
    uint4 v1 = hs[r1*16 + lane];
    add8(v0); add8(v1);
  }
  if (i < e){
    uint4 v0 = hs[csr[i]*16 + lane];
    add8(v0);
  }
  add8(hs[node*16 + lane]);
  float d = dinv[node];
  float4 o0 = {acc[0]*d, acc[1]*d, acc[2]*d, acc[3]*d};
  float4 o1 = {acc[4]*d, acc[5]*d, acc[6]*d, acc[7]*d};
  ((float4*)z)[node*32 + lane*2 + 0] = o0;
  ((float4*)z)[node*32 + lane*2 + 1] = o1;
}

// ---------------- GEMM: out = relu(A @ W + bias), + bn stats ----------------
template<int K, int NWTOT, bool CONCAT, bool AFFINE>
__global__ __launch_bounds__(256) void k_gemm_mlp(
    const float* __restrict__ A0, const float* __restrict__ A1,
    const float* __restrict__ W,
    const float* __restrict__ scale, const float* __restrict__ shift,
    const float* __restrict__ bias,
    float* __restrict__ out, float* __restrict__ gstats, int nrows)
{
  __shared__ float As[32*68];
  __shared__ float Bs[32*128];
  __shared__ float s_sum[128], s_sq[128];
  int m0 = blockIdx.x*64;
  int n0 = blockIdx.y*128;
  int tid  = threadIdx.x;
  int tcol = tid & 31, trow = tid >> 5;
  float acc[8][4] = {};
  constexpr int NCH = (K + 31) / 32;
  for (int ch = 0; ch < NCH; ch++){
    int kc0 = ch*32;
    #pragma unroll
    for (int j = 0; j < 2; j++){
      int fid = tid + j*256;
      int rr = fid >> 3; int k4 = (fid & 7) << 2;
      int row = m0 + rr;
      int kg = kc0 + k4;
      float4 v = {0.f,0.f,0.f,0.f};
      if (row < nrows){
        if constexpr (CONCAT){
          if (kg < 256)      v = *(const float4*)(A0 + (size_t)row*256 + kg);
          else if (kg < 456) v = *(const float4*)(A1 + (size_t)row*200 + (kg-256));
        } else {
          v = *(const float4*)(A0 + (size_t)row*K + kg);
        }
      }
      if constexpr (AFFINE){
        float4 scv = *(const float4*)(scale + kg);
        float4 shv = *(const float4*)(shift + kg);
        v.x = fmaf(v.x, scv.x, shv.x);
        v.y = fmaf(v.y, scv.y, shv.y);
        v.z = fmaf(v.z, scv.z, shv.z);
        v.w = fmaf(v.w, scv.w, shv.w);
      }
      As[(k4+0)*68 + rr] = v.x;
      As[(k4+1)*68 + rr] = v.y;
      As[(k4+2)*68 + rr] = v.z;
      As[(k4+3)*68 + rr] = v.w;
    }
    #pragma unroll
    for (int j = 0; j < 4; j++){
      int fid = tid + j*256;
      int kk = fid >> 5; int c4 = (fid & 31) << 2;
      int kg = kc0 + kk;
      float4 v = {0.f,0.f,0.f,0.f};
      if (kg < K) v = *(const float4*)(W + (size_t)kg*NWTOT + n0 + c4);
      *(float4*)(Bs + kk*128 + c4) = v;
    }
    __syncthreads();
    #pragma unroll
    for (int kk = 0; kk < 32; kk++){
      float4 b  = *(const float4*)(Bs + kk*128 + tcol*4);
      float4 a0 = *(const float4*)(As + kk*68 + trow*8);
      float4 a1 = *(const float4*)(As + kk*68 + trow*8 + 4);
      float a[8] = {a0.x,a0.y,a0.z,a0.w,a1.x,a1.y,a1.z,a1.w};
      #pragma unroll
      for (int r = 0; r < 8; r++){
        acc[r][0] = fmaf(a[r], b.x, acc[r][0]);
        acc[r][1] = fmaf(a[r], b.y, acc[r][1]);
        acc[r][2] = fmaf(a[r], b.z, acc[r][2]);
        acc[r][3] = fmaf(a[r], b.w, acc[r][3]);
      }
    }
    __syncthreads();
  }
  for (int i = tid; i < 128; i += 256){ s_sum[i] = 0.f; s_sq[i] = 0.f; }
  __syncthreads();
  float4 bv = *(const float4*)(bias + n0 + tcol*4);
  float psum[4] = {0,0,0,0}, psq[4] = {0,0,0,0};
  #pragma unroll
  for (int r = 0; r < 8; r++){
    int row = m0 + trow*8 + r;
    if (row < nrows){
      float4 o;
      o.x = fmaxf(acc[r][0] + bv.x, 0.f);
      o.y = fmaxf(acc[r][1] + bv.y, 0.f);
      o.z = fmaxf(acc[r][2] + bv.z, 0.f);
      o.w = fmaxf(acc[r][3] + bv.w, 0.f);
      *(float4*)(out + (size_t)row*NWTOT + n0 + tcol*4) = o;
      psum[0] += o.x; psq[0] += o.x*o.x;
      psum[1] += o.y; psq[1] += o.y*o.y;
      psum[2] += o.z; psq[2] += o.z*o.z;
      psum[3] += o.w; psq[3] += o.w*o.w;
    }
  }
  int f0 = tcol*4;
  atomicAdd(&s_sum[f0+0], psum[0]); atomicAdd(&s_sq[f0+0], psq[0]);
  atomicAdd(&s_sum[f0+1], psum[1]); atomicAdd(&s_sq[f0+1], psq[1]);
  atomicAdd(&s_sum[f0+2], psum[2]); atomicAdd(&s_sq[f0+2], psq[2]);
  atomicAdd(&s_sum[f0+3], psum[3]); atomicAdd(&s_sq[f0+3], psq[3]);
  __syncthreads();
  float* gs = gstats + (size_t)(blockIdx.x & 31)*(2*NWTOT);
  for (int i = tid; i < 128; i += 256){
    atomicAdd(&gs[n0 + i], s_sum[i]);
    atomicAdd(&gs[NWTOT + n0 + i], s_sq[i]);
  }
}

// ---------------- GEMM + fused relu/pool/stats (h2 never materialized) ----------------
template<int K, int NWTOT>
__global__ __launch_bounds__(256) void k_gemm_pool(
    const float* __restrict__ A, const float* __restrict__ W,
    const float* __restrict__ bias, const int* __restrict__ batch,
    float* __restrict__ embsum, float* __restrict__ gstats, int nrows)
{
  __shared__ float As[32*68];
  __shared__ float Bs[32*128];
  __shared__ float s_sum[128], s_sq[128];
  __shared__ int s_batch[64];
  int m0 = blockIdx.x*64;
  int n0 = blockIdx.y*128;
  int tid  = threadIdx.x;
  int tcol = tid & 31, trow = tid >> 5;
  float acc[8][4] = {};
  constexpr int NCH = (K + 31) / 32;
  for (int ch = 0; ch < NCH; ch++){
    int kc0 = ch*32;
    #pragma unroll
    for (int j = 0; j < 2; j++){
      int fid = tid + j*256;
      int rr = fid >> 3; int k4 = (fid & 7) << 2;
      int row = m0 + rr;
      int kg = kc0 + k4;
      float4 v = {0.f,0.f,0.f,0.f};
      if (row < nrows) v = *(const float4*)(A + (size_t)row*K + kg);
      As[(k4+0)*68 + rr] = v.x;
      As[(k4+1)*68 + rr] = v.y;
      As[(k4+2)*68 + rr] = v.z;
      As[(k4+3)*68 + rr] = v.w;
    }
    #pragma unroll
    for (int j = 0; j < 4; j++){
      int fid = tid + j*256;
      int kk = fid >> 5; int c4 = (fid & 31) << 2;
      int kg = kc0 + kk;
      float4 v = *(const float4*)(W + (size_t)kg*NWTOT + n0 + c4);
      *(float4*)(Bs + kk*128 + c4) = v;
    }
    __syncthreads();
    #pragma unroll
    for (int kk = 0; kk < 32; kk++){
      float4 b  = *(const float4*)(Bs + kk*128 + tcol*4);
      float4 a0 = *(const float4*)(As + kk*68 + trow*8);
      float4 a1 = *(const float4*)(As + kk*68 + trow*8 + 4);
      float a[8] = {a0.x,a0.y,a0.z,a0.w,a1.x,a1.y,a1.z,a1.w};
      #pragma unroll
      for (int r = 0; r < 8; r++){
        acc[r][0] = fmaf(a[r], b.x, acc[r][0]);
        acc[r][1] = fmaf(a[r], b.y, acc[r][1]);
        acc[r][2] = fmaf(a[r], b.z, acc[r][2]);
        acc[r][3] = fmaf(a[r], b.w, acc[r][3]);
      }
    }
    __syncthreads();
  }
  if (tid < 64) s_batch[tid] = (m0 + tid < nrows) ? batch[m0 + tid] : -1;
  for (int i = tid; i < 128; i += 256){ s_sum[i] = 0.f; s_sq[i] = 0.f; }
  __syncthreads();
  float4 bv = *(const float4*)(bias + n0 + tcol*4);
  float psum[4] = {0,0,0,0}, psq[4] = {0,0,0,0};
  float run[4] = {0,0,0,0};
  int runb = -1;
  #pragma unroll
  for (int r = 0; r < 8; r++){
    int row = m0 + trow*8 + r;
    if (row < nrows){
      float ox = fmaxf(acc[r][0] + bv.x, 0.f);
      float oy = fmaxf(acc[r][1] + bv.y, 0.f);
      float oz = fmaxf(acc[r][2] + bv.z, 0.f);
      float ow = fmaxf(acc[r][3] + bv.w, 0.f);
      psum[0] += ox; psq[0] += ox*ox;
      psum[1] += oy; psq[1] += oy*oy;
      psum[2] += oz; psq[2] += oz*oz;
      psum[3] += ow; psq[3] += ow*ow;
      int b = s_batch[trow*8 + r];
      if (b != runb){
        if (runb >= 0){
          float* es = embsum + (size_t)runb*NWTOT + n0 + tcol*4;
          atomicAdd(es+0, run[0]); atomicAdd(es+1, run[1]);
          atomicAdd(es+2, run[2]); atomicAdd(es+3, run[3]);
        }
        runb = b;
        run[0] = ox; run[1] = oy; run[2] = oz; run[3] = ow;
      } else {
        run[0] += ox; run[1] += oy; run[2] += oz; run[3] += ow;
      }
    }
  }
  if (runb >= 0){
    float* es = embsum + (size_t)runb*NWTOT + n0 + tcol*4;
    atomicAdd(es+0, run[0]); atomicAdd(es+1, run[1]);
    atomicAdd(es+2, run[2]); atomicAdd(es+3, run[3]);
  }
  int f0 = tcol*4;
  atomicAdd(&s_sum[f0+0], psum[0]); atomicAdd(&s_sq[f0+0], psq[0]);
  atomicAdd(&s_sum[f0+1], psum[1]); atomicAdd(&s_sq[f0+1], psq[1]);
  atomicAdd(&s_sum[f0+2], psum[2]); atomicAdd(&s_sq[f0+2], psq[2]);
  atomicAdd(&s_sum[f0+3], psum[3]); atomicAdd(&s_sq[f0+3], psq[3]);
  __syncthreads();
  float* gs = gstats + (size_t)(blockIdx.x & 31)*(2*NWTOT);
  for (int i = tid; i < 128; i += 256){
    atomicAdd(&gs[n0 + i], s_sum[i]);
    atomicAdd(&gs[NWTOT + n0 + i], s_sq[i]);
  }
}

// ---------------- final: out[g] = bn4(a2[g,:]) . mW3 + mb3 ----------------
__global__ __launch_bounds__(256) void k_final(
    const float* __restrict__ a2, const float* __restrict__ sc, const float* __restrict__ sh,
    const float* __restrict__ w, const float* __restrict__ b, float* __restrict__ out, int G)
{
  int gid  = blockIdx.x*blockDim.x + threadIdx.x;
  int wid  = gid >> 6;
  int lane = gid & 63;
  if (wid >= G) return;
  float2 v = ((const float2*)(a2 + (size_t)wid*128))[lane];
  int k = lane*2;
  float s = fmaf(v.x, sc[k], sh[k]) * w[k] + fmaf(v.y, sc[k+1], sh[k+1]) * w[k+1];
  #pragma unroll
  for (int o = 32; o > 0; o >>= 1) s += __shfl_down(s, o, 64);
  if (lane == 0) out[wid] = s + b[0];
}

// ---------------- launcher ----------------
extern "C" void kernel_launch(void* const* d_in, const int* in_sizes, int n_in,
                              void* d_out, int out_size, void* d_ws, size_t ws_size,
                              hipStream_t stream)
{
  (void)n_in; (void)out_size; (void)ws_size;
  const float* x    = (const float*)d_in[0];
  const int*   ei   = (const int*)d_in[1];
  const int*   batch= (const int*)d_in[2];
  const float* rdk  = (const float*)d_in[3];
  const float* W1   = (const float*)d_in[4];
  const float* b1   = (const float*)d_in[5];
  const float* g1   = (const float*)d_in[6];
  const float* be1  = (const float*)d_in[7];
  const float* W2   = (const float*)d_in[8];
  const float* b2   = (const float*)d_in[9];
  const float* g2   = (const float*)d_in[10];
  const float* be2  = (const float*)d_in[11];
  const float* mW1  = (const float*)d_in[12];
  const float* mb1  = (const float*)d_in[13];
  const float* mg1  = (const float*)d_in[14];
  const float* mbe1 = (const float*)d_in[15];
  const float* mW2  = (const float*)d_in[16];
  const float* mb2  = (const float*)d_in[17];
  const float* mg2  = (const float*)d_in[18];
  const float* mbe2 = (const float*)d_in[19];
  const float* mW3  = (const float*)d_in[20];
  const float* mb3  = (const float*)d_in[21];

  const int N = in_sizes[0] / 64;
  const int E = in_sizes[1] / 2;
  const int G = in_sizes[3] / 200;
  const int* erow = ei;
  const int* ecol = ei + E;

  size_t off = 0;
  auto alloc = [&](size_t bytes)->char*{
    char* p = (char*)d_ws + off;
    off += (bytes + 255) & ~(size_t)255;
    return p;
  };
  int*   indeg  = (int*)  alloc((size_t)N*4);
  int*   offs   = (int*)  alloc(((size_t)N+1)*4);
  int*   cursor = (int*)  alloc((size_t)N*4);
  int*   csr    = (int*)  alloc((size_t)E*4);
  float* dinv   = (float*)alloc((size_t)N*4);
  int*   bsum   = (int*)  alloc(1024*4);
  uint16_t* xs  = (uint16_t*)alloc((size_t)N*64*2);
  float* z1     = (float*)alloc((size_t)N*64*4);
  float* h1     = (float*)alloc((size_t)N*128*4);
  uint16_t* hs  = (uint16_t*)alloc((size_t)N*128*2);
  float* z2     = (float*)alloc((size_t)N*128*4);
  float* embsum = (float*)alloc((size_t)G*256*4);
  int*   cnt    = (int*)  alloc((size_t)G*4);
  float* emb    = (float*)alloc((size_t)G*256*4);
  float* a1     = (float*)alloc((size_t)G*256*4);
  float* a2     = (float*)alloc((size_t)G*128*4);
  float* gstats = (float*)alloc((size_t)4*32*2*256*4);
  float* scsh   = (float*)alloc((size_t)4*2*256*4);

  float* gs0 = gstats;
  float* gs1 = gstats + 32*2*256;
  float* gs2 = gstats + 2*32*2*256;
  float* gs3 = gstats + 3*32*2*256;
  float* sc1 = scsh;        float* sh1 = scsh + 256;
  float* sc2 = scsh + 512;  float* sh2 = scsh + 768;
  float* sc3 = scsh + 1024; float* sh3 = scsh + 1280;
  float* sc4 = scsh + 1536; float* sh4 = scsh + 1792;

  hipMemsetAsync(indeg,  0, (size_t)N*4, stream);
  hipMemsetAsync(gstats, 0, (size_t)4*32*2*256*4, stream);
  hipMemsetAsync(embsum, 0, (size_t)G*256*4, stream);
  hipMemsetAsync(cnt,    0, (size_t)G*4, stream);

  int nblkE = (E + 255) / 256;
  int nblkN = (N + 255) / 256;
  int nscan = (N + 1023) / 1024;
  int mblk  = (N + 63) / 64;
  int gblk  = (G + 63) / 64;

  k_count<<<nblkE,256,0,stream>>>(ecol, indeg, E);
  k_scan1<<<nscan,256,0,stream>>>(indeg, offs, bsum, N);
  k_scan2<<<1,128,0,stream>>>(bsum, nscan);
  k_scan3<<<nblkN,256,0,stream>>>(offs, cursor, bsum, N, E);
  k_dinv<<<nblkN,256,0,stream>>>(indeg, dinv, N);
  k_fill<<<nblkE,256,0,stream>>>(erow, ecol, cursor, csr, E);
  k_cnt<<<nblkN,256,0,stream>>>(batch, cnt, N);

  // layer 1: aggregate-first (F=64), then GEMM 64->128 with fused relu+stats
  k_prep1<<<(N*16+255)/256,256,0,stream>>>((const float4*)x, dinv, (ushort4*)xs, N);
  k_agg1<<<(N+31)/32,256,0,stream>>>((const uint4*)xs, offs, csr, dinv, z1, N);
  k_gemm_mlp<64,128,false,false><<<dim3(mblk,1),256,0,stream>>>(z1, nullptr, W1, nullptr, nullptr, b1, h1, gs0, N);
  k_bnfin<<<1,256,0,stream>>>(gs0, 128, 1.0f/(float)N, g1, be1, sc1, sh1);

  // layer 2: fold bn1 affine + dinv into bf16 payload, aggregate (F=128), GEMM 128->256 + fused pool
  k_prep2<<<(N*32+255)/256,256,0,stream>>>((const float4*)h1, dinv, (const float4*)sc1, (const float4*)sh1, (ushort4*)hs, N);
  k_agg2<<<(N+15)/16,256,0,stream>>>((const uint4*)hs, offs, csr, dinv, z2, N);
  k_gemm_pool<128,256><<<dim3(mblk,2),256,0,stream>>>(z2, W2, b2, batch, embsum, gs1, N);
  k_bnfin<<<1,256,0,stream>>>(gs1, 256, 1.0f/(float)N, g2, be2, sc2, sh2);

  // graph head
  k_emb<<<(G*64+255)/256,256,0,stream>>>(embsum, cnt, sc2, sh2, emb, G);
  k_gemm_mlp<456,256,true,false><<<dim3(gblk,2),256,0,stream>>>(emb, rdk, mW1, nullptr, nullptr, mb1, a1, gs2, G);
  k_bnfin<<<1,256,0,stream>>>(gs2, 256, 1.0f/(float)G, mg1, mbe1, sc3, sh3);
  k_gemm_mlp<256,128,false,true><<<dim3(gblk,1),256,0,stream>>>(a1, nullptr, mW2, sc3, sh3, mb2, a2, gs3, G);
  k_bnfin<<<1,256,0,stream>>>(gs3, 128, 1.0f/(float)G, mg2, mbe2, sc4, sh4);
  k_final<<<(G+3)/4,256,0,stream>>>(a2, sc4, sh4, mW3, mb3, (float*)d_out, G);
}